// Round 13
// baseline (487.874 us; speedup 1.0000x reference)
//
#include <hip/hip_runtime.h>

// B=32768, K=16, D=256, H=2, HD=128
#define Bsz 32768
#define BR  16           // rows per block; 4 rows per wave, wave-autonomous
#define SCALE 0.08838834764831845f   // 1/sqrt(128)

typedef __attribute__((ext_vector_type(4))) float f32x4;
typedef __attribute__((ext_vector_type(4))) unsigned short us4;
typedef __attribute__((ext_vector_type(4))) unsigned int ui4;
typedef __attribute__((ext_vector_type(2))) unsigned int ui2;
typedef _Float16 __attribute__((ext_vector_type(2))) h2;

static __device__ __forceinline__ unsigned int pk16(float a, float b){
  return __builtin_bit_cast(unsigned int, __builtin_amdgcn_cvt_pkrtz(a, b));
}
static __device__ __forceinline__ h2 uph(unsigned int u){
  return __builtin_bit_cast(h2, u);
}
static __device__ __forceinline__ float h2f(unsigned short h){
  return (float)__builtin_bit_cast(_Float16, h);
}
#define FDOT2(a, b, c) __builtin_amdgcn_fdot2((a), (b), (c), false)

// ---------------------------------------------------------------------------
// Prep (identical to passing round 12): f16 k-pair-packed weights, k-major.
//   W1P uint [128][640]: cols 0..511 -> M_h[k][m] (h=n>>8,m=n&255); 512..639 Wc
//   W2P uint [128][256]: Wv^T packed;  W3P uint [128][128]: Wx^T packed
// ---------------------------------------------------------------------------
__global__ void prep_kernel(const float* __restrict__ Wq, const float* __restrict__ Wk,
                            const float* __restrict__ Wv, const float* __restrict__ Wc,
                            const float* __restrict__ Wx, unsigned int* __restrict__ wsp){
  unsigned int* W1P = wsp;                 // [128][640]
  unsigned int* W2P = wsp + 128*640;       // [128][256]
  unsigned int* W3P = W2P + 128*256;       // [128][128]
  const int n = blockIdx.x;
  const int k = threadIdx.x;
  float val;
  if (n < 512){
    const int h = n >> 8, m = n & 255;
    const float* wq = Wq + h*128*256 + k;
    const float* wk = Wk + h*128*256 + m;
    float s = 0.f;
    for (int d = 0; d < 128; ++d) s += wq[d*256] * wk[d*256];
    val = s;
  } else if (n < 640){
    val = Wc[(n-512)*256 + k];
  } else if (n < 896){
    val = Wv[(n-640)*256 + k];
  } else {
    val = Wx[(n-896)*256 + k];
  }
  const float vo = __shfl_xor(val, 1, 64);
  if ((k & 1) == 0){
    const unsigned int p = pk16(val, vo);
    const int kp = k >> 1;
    if (n < 640)      W1P[kp*640 + n] = p;
    else if (n < 896) W2P[kp*256 + (n-640)] = p;
    else              W3P[kp*128 + (n-896)] = p;
  }
}

// ---------------------------------------------------------------------------
// Fused kernel, BR=16, 256 threads (4 waves), ZERO BARRIERS. Wave w owns rows
// 4w..4w+3 in every phase; all LDS wave-local; in-order WAR overlays only.
// Occupancy round: LDS 16.6 KB -> up to 8 blocks/CU; grid 2048.
// Thread map A/C/E: lh=lane>>5 -> rows r0=4w+2lh, r1=r0+1; ct=lane&31 -> cols.
// LDS us[16][520] per-row cell map (us offset = float col):
//   [256..511]: center f16 pairs (stage..A) -> ctil cols 256..511 (A2..B)
//               -> wbuf (B) -> agg1 (B..C)
//   [0..255]  : ctil cols 0..255 (A1..B) -> agg0 (B..C) -> ctx_n (C..E)
// ---------------------------------------------------------------------------
__global__ __launch_bounds__(256, 6) void fused_kernel(
    const float* __restrict__ center, const float* __restrict__ nbr,
    const float* __restrict__ ew, const float* __restrict__ gamma,
    const float* __restrict__ beta, const unsigned int* __restrict__ Wall,
    float* __restrict__ out)
{
  __shared__ __align__(16) unsigned short s_ctil[BR*520];

  const int tid  = threadIdx.x;
  const int wid  = tid >> 6;
  const int lane = tid & 63;
  const int b0   = blockIdx.x * BR;

  const unsigned int* W1P = Wall;               // [128][640]
  const unsigned int* W2P = Wall + 128*640;     // [128][256]
  const unsigned int* W3P = W2P + 128*256;      // [128][128]

  const int lh = lane >> 5;    // 0..1 (row-pair half)
  const int ct = lane & 31;    // 0..31 (col quad)
  const int r0 = 4*wid + 2*lh;
  const int r1 = r0 + 1;

  // ---- stage center rows 4w..4w+3 as packed f16 pairs -> cells 256..511 ----
  {
    const int sr = 4*wid + (lane >> 4);   // wave-local rows
    const int fc = (lane & 15) * 16;      // float col base
    const float* cp = center + ((long)(b0 + sr) << 8) + fc;
    #pragma unroll
    for (int it = 0; it < 2; ++it){
      float4 a = *(const float4*)(cp + it*8);
      float4 b = *(const float4*)(cp + it*8 + 4);
      ui4 v = {pk16(a.x,a.y), pk16(a.z,a.w), pk16(b.x,b.y), pk16(b.z,b.w)};
      *(ui4*)&s_ctil[sr*520 + 256 + fc + it*8] = v;
    }
  }
  // no barrier: wave-local

  // ---- Phase A pass 1: tiles {0,1,4} -> ctil cols 0..255 + out-left ----
  {
    f32x4 acc[2][3];
    #pragma unroll
    for (int rr = 0; rr < 2; ++rr)
      #pragma unroll
      for (int t = 0; t < 3; ++t) acc[rr][t] = (f32x4){0,0,0,0};
    #pragma unroll 1
    for (int k0 = 0; k0 < 256; k0 += 8){
      ui4 a8[2];
      a8[0] = *(const ui4*)&s_ctil[r0*520 + 256 + k0];
      a8[1] = *(const ui4*)&s_ctil[r1*520 + 256 + k0];
      #pragma unroll
      for (int kp = 0; kp < 4; ++kp){
        const unsigned int* wrow = W1P + ((k0>>1) + kp)*640;
        const ui4 w0 = ((const ui4*)(wrow      ))[ct];
        const ui4 w1 = ((const ui4*)(wrow + 128))[ct];
        const ui4 w4 = ((const ui4*)(wrow + 512))[ct];
        #pragma unroll
        for (int rr = 0; rr < 2; ++rr){
          const h2 a2 = uph(a8[rr][kp]);
          #pragma unroll
          for (int j = 0; j < 4; ++j){
            acc[rr][0][j] = FDOT2(a2, uph(w0[j]), acc[rr][0][j]);
            acc[rr][1][j] = FDOT2(a2, uph(w1[j]), acc[rr][1][j]);
            acc[rr][2][j] = FDOT2(a2, uph(w4[j]), acc[rr][2][j]);
          }
        }
      }
    }
    #pragma unroll
    for (int rr = 0; rr < 2; ++rr){
      const int r = (rr == 0) ? r0 : r1;
      ui2 v0 = {pk16(acc[rr][0][0], acc[rr][0][1]), pk16(acc[rr][0][2], acc[rr][0][3])};
      ui2 v1 = {pk16(acc[rr][1][0], acc[rr][1][1]), pk16(acc[rr][1][2], acc[rr][1][3])};
      *(ui2*)&s_ctil[r*520 + ct*4]       = v0;    // ctil cols ct*4..+3
      *(ui2*)&s_ctil[r*520 + 128 + ct*4] = v1;    // ctil cols 128+..
      *(f32x4*)&out[((long)(b0 + r) << 8) + ct*4] = acc[rr][2];
    }
  }

  // ---- Phase A pass 2: tiles {2,3} -> ctil cols 256..511 (post-loop write) ----
  {
    f32x4 acc[2][2];
    #pragma unroll
    for (int rr = 0; rr < 2; ++rr){ acc[rr][0] = (f32x4){0,0,0,0}; acc[rr][1] = (f32x4){0,0,0,0}; }
    #pragma unroll 1
    for (int k0 = 0; k0 < 256; k0 += 8){
      ui4 a8[2];
      a8[0] = *(const ui4*)&s_ctil[r0*520 + 256 + k0];
      a8[1] = *(const ui4*)&s_ctil[r1*520 + 256 + k0];
      #pragma unroll
      for (int kp = 0; kp < 4; ++kp){
        const unsigned int* wrow = W1P + ((k0>>1) + kp)*640;
        const ui4 w2 = ((const ui4*)(wrow + 256))[ct];
        const ui4 w3 = ((const ui4*)(wrow + 384))[ct];
        #pragma unroll
        for (int rr = 0; rr < 2; ++rr){
          const h2 a2 = uph(a8[rr][kp]);
          #pragma unroll
          for (int j = 0; j < 4; ++j){
            acc[rr][0][j] = FDOT2(a2, uph(w2[j]), acc[rr][0][j]);
            acc[rr][1][j] = FDOT2(a2, uph(w3[j]), acc[rr][1][j]);
          }
        }
      }
    }
    // all center reads (all lanes of this wave) precede these in-order writes
    #pragma unroll
    for (int rr = 0; rr < 2; ++rr){
      const int r = (rr == 0) ? r0 : r1;
      ui2 v0 = {pk16(acc[rr][0][0], acc[rr][0][1]), pk16(acc[rr][0][2], acc[rr][0][3])};
      ui2 v1 = {pk16(acc[rr][1][0], acc[rr][1][1]), pk16(acc[rr][1][2], acc[rr][1][3])};
      *(ui2*)&s_ctil[r*520 + 256 + ct*4] = v0;    // ctil cols 256+..
      *(ui2*)&s_ctil[r*520 + 384 + ct*4] = v1;    // ctil cols 384+..
    }
  }
  // no barrier: ctil rows wave-local

  // ---- Phase B: attention, 4 rows/wave; reduce-scatter scores ----
  {
    const int myk = ((lane>>4)&1)*8 + ((lane>>3)&1)*4 + ((lane>>2)&1)*2 + ((lane>>1)&1);
    const int myh = lane >> 5;
    #pragma unroll 1
    for (int rr = 0; rr < 4; ++rr){
      const int r = 4*wid + rr;
      const long b = b0 + r;
      float4 c0, c1;
      {
        us4 h0 = *(const us4*)&s_ctil[r*520 + lane*4];
        us4 h1 = *(const us4*)&s_ctil[r*520 + 256 + lane*4];
        c0.x=h2f(h0[0]); c0.y=h2f(h0[1]); c0.z=h2f(h0[2]); c0.w=h2f(h0[3]);
        c1.x=h2f(h1[0]); c1.y=h2f(h1[1]); c1.z=h2f(h1[2]); c1.w=h2f(h1[3]);
      }
      float4 xv[16];
      const float* npt = nbr + ((b << 4) << 8) + lane*4;
      #pragma unroll
      for (int k = 0; k < 16; ++k) xv[k] = *(const float4*)(npt + (k << 8));
      float P0[16], P1[16];
      #pragma unroll
      for (int k = 0; k < 16; ++k){
        P0[k] = xv[k].x*c0.x + xv[k].y*c0.y + xv[k].z*c0.z + xv[k].w*c0.w;
        P1[k] = xv[k].x*c1.x + xv[k].y*c1.y + xv[k].z*c1.z + xv[k].w*c1.w;
      }
      // reduce-scatter: masks 32,16,8,4,2, then final 1
      const int b5 = lane & 32, b4 = lane & 16, b3 = lane & 8, b2 = lane & 4, b1 = lane & 2;
      float Q[16];
      #pragma unroll
      for (int j = 0; j < 16; ++j){
        const float give = b5 ? P0[j] : P1[j];
        const float keep = b5 ? P1[j] : P0[j];
        Q[j] = keep + __shfl_xor(give, 32, 64);
      }
      float R[8];
      #pragma unroll
      for (int j = 0; j < 8; ++j){
        const float give = b4 ? Q[j] : Q[8+j];
        const float keep = b4 ? Q[8+j] : Q[j];
        R[j] = keep + __shfl_xor(give, 16, 64);
      }
      float S[4];
      #pragma unroll
      for (int j = 0; j < 4; ++j){
        const float give = b3 ? R[j] : R[4+j];
        const float keep = b3 ? R[4+j] : R[j];
        S[j] = keep + __shfl_xor(give, 8, 64);
      }
      float T[2];
      #pragma unroll
      for (int j = 0; j < 2; ++j){
        const float give = b2 ? S[j] : S[2+j];
        const float keep = b2 ? S[2+j] : S[j];
        T[j] = keep + __shfl_xor(give, 4, 64);
      }
      float U;
      {
        const float give = b1 ? T[0] : T[1];
        const float keep = b1 ? T[1] : T[0];
        U = keep + __shfl_xor(give, 2, 64);
      }
      const float sfull = U + __shfl_xor(U, 1, 64);   // s[myh][myk]
      const float erk = ew[b*16 + myk];
      const float e = __expf(sfull*SCALE + erk);      // scores O(1): no max-sub
      float dn = e;
      dn += __shfl_xor(dn, 2, 64);
      dn += __shfl_xor(dn, 4, 64);
      dn += __shfl_xor(dn, 8, 64);
      dn += __shfl_xor(dn, 16, 64);
      const float w = e / dn;
      // broadcast via wave-local overlay of head1-ctil cells (c1 already read)
      float* wbuf = (float*)&s_ctil[r*520 + 256];
      wbuf[myh*16 + myk] = w;                         // 2 lanes same addr, same value
      f32x4 wv[8];
      #pragma unroll
      for (int t = 0; t < 8; ++t) wv[t] = ((const f32x4*)wbuf)[t];
      float4 agg0 = {0,0,0,0}, agg1 = {0,0,0,0};
      #pragma unroll
      for (int k = 0; k < 16; ++k){
        const float w0 = wv[k>>2][k&3];
        const float w1 = wv[4 + (k>>2)][k&3];
        agg0.x += w0*xv[k].x; agg0.y += w0*xv[k].y; agg0.z += w0*xv[k].z; agg0.w += w0*xv[k].w;
        agg1.x += w1*xv[k].x; agg1.y += w1*xv[k].y; agg1.z += w1*xv[k].z; agg1.w += w1*xv[k].w;
      }
      ui2 v0 = {pk16(agg0.x, agg0.y), pk16(agg0.z, agg0.w)};
      ui2 v1 = {pk16(agg1.x, agg1.y), pk16(agg1.z, agg1.w)};
      *(ui2*)&s_ctil[r*520 + lane*4]       = v0;   // agg0 (WAR on own cells)
      *(ui2*)&s_ctil[r*520 + 256 + lane*4] = v1;   // agg1 (overwrites wbuf after read)
    }
  }
  // no barrier: agg rows wave-local

  // ---- Phase C (+fused LayerNorm): ctx in registers -> ctx_n packed f16 ----
  {
    f32x4 cacc[2][2];
    #pragma unroll
    for (int rr = 0; rr < 2; ++rr){ cacc[rr][0] = (f32x4){0,0,0,0}; cacc[rr][1] = (f32x4){0,0,0,0}; }
    #pragma unroll 1
    for (int k0 = 0; k0 < 256; k0 += 8){
      ui4 a0[2], a1[2];
      a0[0] = *(const ui4*)&s_ctil[r0*520 + k0];
      a0[1] = *(const ui4*)&s_ctil[r1*520 + k0];
      a1[0] = *(const ui4*)&s_ctil[r0*520 + 256 + k0];
      a1[1] = *(const ui4*)&s_ctil[r1*520 + 256 + k0];
      #pragma unroll
      for (int kp = 0; kp < 4; ++kp){
        const unsigned int* wrow = W2P + ((k0>>1) + kp)*256;
        const ui4 w0 = ((const ui4*)(wrow      ))[ct];   // ctx cols 0..127 (head0)
        const ui4 w1 = ((const ui4*)(wrow + 128))[ct];   // ctx cols 128..255 (head1)
        #pragma unroll
        for (int rr = 0; rr < 2; ++rr){
          const h2 x0 = uph(a0[rr][kp]);
          const h2 x1 = uph(a1[rr][kp]);
          #pragma unroll
          for (int j = 0; j < 4; ++j){
            cacc[rr][0][j] = FDOT2(x0, uph(w0[j]), cacc[rr][0][j]);
            cacc[rr][1][j] = FDOT2(x1, uph(w1[j]), cacc[rr][1][j]);
          }
        }
      }
    }
    // fused LayerNorm across the 32 ct-lanes (masks never cross the lh bit)
    const f32x4 gv0 = ((const f32x4*)gamma)[ct], gv1 = ((const f32x4*)gamma)[32 + ct];
    const f32x4 bv0 = ((const f32x4*)beta )[ct], bv1 = ((const f32x4*)beta )[32 + ct];
    #pragma unroll
    for (int rr = 0; rr < 2; ++rr){
      float s = 0.f, q = 0.f;
      #pragma unroll
      for (int t = 0; t < 2; ++t)
        #pragma unroll
        for (int j = 0; j < 4; ++j){
          const float x = cacc[rr][t][j];
          s += x; q += x*x;
        }
      #pragma unroll
      for (int m = 16; m >= 1; m >>= 1){
        s += __shfl_xor(s, m, 64);
        q += __shfl_xor(q, m, 64);
      }
      const float mu  = s * (1.f/256.f);
      const float var = q * (1.f/256.f) - mu*mu;
      const float rs  = rsqrtf(var + 1e-5f);
      const int r = (rr == 0) ? r0 : r1;
      float y0[4], y1[4];
      #pragma unroll
      for (int j = 0; j < 4; ++j){
        y0[j] = (cacc[rr][0][j] - mu)*rs*gv0[j] + bv0[j];
        y1[j] = (cacc[rr][1][j] - mu)*rs*gv1[j] + bv1[j];
      }
      ui2 v0 = {pk16(y0[0], y0[1]), pk16(y0[2], y0[3])};
      ui2 v1 = {pk16(y1[0], y1[1]), pk16(y1[2], y1[3])};
      *(ui2*)&s_ctil[r*520 + ct*4]       = v0;   // ctx_n cols ct*4..+3
      *(ui2*)&s_ctil[r*520 + 128 + ct*4] = v1;   // ctx_n cols 128+..
    }
  }
  // no barrier: ctx_n rows wave-local

  // ---- Phase E: out-right = ctx_n @ Wx^T ----
  {
    f32x4 eacc[2] = {{0,0,0,0},{0,0,0,0}};
    #pragma unroll 1
    for (int k0 = 0; k0 < 256; k0 += 8){
      ui4 a[2];
      a[0] = *(const ui4*)&s_ctil[r0*520 + k0];
      a[1] = *(const ui4*)&s_ctil[r1*520 + k0];
      #pragma unroll
      for (int kp = 0; kp < 4; ++kp){
        const ui4 w = ((const ui4*)(W3P + ((k0>>1) + kp)*128))[ct];
        #pragma unroll
        for (int rr = 0; rr < 2; ++rr){
          const h2 x = uph(a[rr][kp]);
          #pragma unroll
          for (int j = 0; j < 4; ++j)
            eacc[rr][j] = FDOT2(x, uph(w[j]), eacc[rr][j]);
        }
      }
    }
    *(f32x4*)&out[((long)(b0 + r0) << 8) + 128 + ct*4] = eacc[0];
    *(f32x4*)&out[((long)(b0 + r1) << 8) + 128 + ct*4] = eacc[1];
  }
}

extern "C" void kernel_launch(void* const* d_in, const int* in_sizes, int n_in,
                              void* d_out, int out_size, void* d_ws, size_t ws_size,
                              hipStream_t stream){
  const float* center = (const float*)d_in[0];
  const float* nbr    = (const float*)d_in[1];
  const float* ew     = (const float*)d_in[2];
  const float* Wq     = (const float*)d_in[3];
  const float* Wk     = (const float*)d_in[4];
  const float* Wv     = (const float*)d_in[5];
  const float* Wc     = (const float*)d_in[6];
  const float* Wx     = (const float*)d_in[7];
  const float* gamma  = (const float*)d_in[8];
  const float* beta   = (const float*)d_in[9];
  (void)in_sizes; (void)n_in; (void)out_size;

  unsigned int* W = (unsigned int*)d_ws;   // 512 KiB of workspace
  (void)ws_size;

  prep_kernel<<<1024, 256, 0, stream>>>(Wq, Wk, Wv, Wc, Wx, W);
  fused_kernel<<<Bsz/BR, 256, 0, stream>>>(center, nbr, ew, gamma, beta, W, (float*)d_out);
}

// Round 14
// 253.574 us; speedup vs baseline: 1.9240x; 1.9240x over previous
//
#include <hip/hip_runtime.h>

// B=32768, K=16, D=256, H=2, HD=128
#define Bsz 32768
#define BR  32           // rows per block; 8 rows per wave, wave-autonomous
#define SCALE 0.08838834764831845f   // 1/sqrt(128)

typedef __attribute__((ext_vector_type(4))) float f32x4;
typedef __attribute__((ext_vector_type(4))) unsigned short us4;
typedef __attribute__((ext_vector_type(4))) unsigned int ui4;
typedef __attribute__((ext_vector_type(2))) unsigned int ui2;
typedef _Float16 __attribute__((ext_vector_type(2))) h2;

static __device__ __forceinline__ unsigned int pk16(float a, float b){
  return __builtin_bit_cast(unsigned int, __builtin_amdgcn_cvt_pkrtz(a, b));
}
static __device__ __forceinline__ h2 uph(unsigned int u){
  return __builtin_bit_cast(h2, u);
}
static __device__ __forceinline__ float h2f(unsigned short h){
  return (float)__builtin_bit_cast(_Float16, h);
}
#define FDOT2(a, b, c) __builtin_amdgcn_fdot2((a), (b), (c), false)

// ---------------------------------------------------------------------------
// Prep (identical to passing rounds 12/13): f16 k-pair-packed weights, k-major.
//   W1P uint [128][640]: cols 0..511 -> M_h[k][m] (h=n>>8,m=n&255); 512..639 Wc
//   W2P uint [128][256]: Wv^T packed;  W3P uint [128][128]: Wx^T packed
// ---------------------------------------------------------------------------
__global__ void prep_kernel(const float* __restrict__ Wq, const float* __restrict__ Wk,
                            const float* __restrict__ Wv, const float* __restrict__ Wc,
                            const float* __restrict__ Wx, unsigned int* __restrict__ wsp){
  unsigned int* W1P = wsp;                 // [128][640]
  unsigned int* W2P = wsp + 128*640;       // [128][256]
  unsigned int* W3P = W2P + 128*256;       // [128][128]
  const int n = blockIdx.x;
  const int k = threadIdx.x;
  float val;
  if (n < 512){
    const int h = n >> 8, m = n & 255;
    const float* wq = Wq + h*128*256 + k;
    const float* wk = Wk + h*128*256 + m;
    float s = 0.f;
    for (int d = 0; d < 128; ++d) s += wq[d*256] * wk[d*256];
    val = s;
  } else if (n < 640){
    val = Wc[(n-512)*256 + k];
  } else if (n < 896){
    val = Wv[(n-640)*256 + k];
  } else {
    val = Wx[(n-896)*256 + k];
  }
  const float vo = __shfl_xor(val, 1, 64);
  if ((k & 1) == 0){
    const unsigned int p = pk16(val, vo);
    const int kp = k >> 1;
    if (n < 640)      W1P[kp*640 + n] = p;
    else if (n < 896) W2P[kp*256 + (n-640)] = p;
    else              W3P[kp*128 + (n-896)] = p;
  }
}

// ---------------------------------------------------------------------------
// Fused kernel = round 12 structure (BR=32, 4 waves, ZERO BARRIERS, wave w
// owns rows 8w..8w+7, fdot2 GEMMs, single 33.3 KB LDS buffer, 4 blocks/CU)
// + DEPTH-2 REGISTER PREFETCH of weights in A1/A2/C/E (named ping-pong
// buffers, each covering 2 kp-blocks of compute). Accumulation order is
// unchanged -> bit-identical results vs round 12.
// ---------------------------------------------------------------------------
__global__ __launch_bounds__(256, 4) void fused_kernel(
    const float* __restrict__ center, const float* __restrict__ nbr,
    const float* __restrict__ ew, const float* __restrict__ gamma,
    const float* __restrict__ beta, const unsigned int* __restrict__ Wall,
    float* __restrict__ out)
{
  __shared__ __align__(16) unsigned short s_ctil[BR*520];

  const int tid  = threadIdx.x;
  const int wid  = tid >> 6;
  const int lane = tid & 63;
  const int b0   = blockIdx.x * BR;

  const unsigned int* W1P = Wall;               // [128][640]
  const unsigned int* W2P = Wall + 128*640;     // [128][256]
  const unsigned int* W3P = W2P + 128*256;      // [128][128]

  const int rt = tid >> 5;     // 0..7  (rows 4rt..4rt+3)
  const int ct = tid & 31;     // 0..31 (col quad)

  // ---- stage center rows 8w..8w+7 as packed f16 pairs -> cells 256..511 ----
  {
    const int sr = tid >> 3;            // 0..31, wave-local rows
    const int fc = (tid & 7) * 32;      // float col base
    const float* cp = center + ((long)(b0 + sr) << 8) + fc;
    #pragma unroll
    for (int it = 0; it < 4; ++it){
      float4 a = *(const float4*)(cp + it*8);
      float4 b = *(const float4*)(cp + it*8 + 4);
      ui4 v = {pk16(a.x,a.y), pk16(a.z,a.w), pk16(b.x,b.y), pk16(b.z,b.w)};
      *(ui4*)&s_ctil[sr*520 + 256 + fc + it*8] = v;
    }
  }
  // no barrier: wave-local

  // ---- Phase A pass 1: tiles {0,1,4} -> ctil cols 0..255 + out-left ----
  {
    f32x4 acc[4][3];
    #pragma unroll
    for (int rr = 0; rr < 4; ++rr)
      #pragma unroll
      for (int t = 0; t < 3; ++t) acc[rr][t] = (f32x4){0,0,0,0};

    #define LDW1(p0_,p1_,p2_,p3_,p4_,p5_, kprow) { \
      const unsigned int* _w0 = W1P + (kprow)*640; \
      const unsigned int* _w1 = _w0 + 640; \
      p0_ = ((const ui4*)(_w0      ))[ct]; \
      p1_ = ((const ui4*)(_w0 + 128))[ct]; \
      p2_ = ((const ui4*)(_w0 + 512))[ct]; \
      p3_ = ((const ui4*)(_w1      ))[ct]; \
      p4_ = ((const ui4*)(_w1 + 128))[ct]; \
      p5_ = ((const ui4*)(_w1 + 512))[ct]; }
    #define CMP1(kp, q0_, q1_, q2_) { \
      _Pragma("unroll") \
      for (int rr = 0; rr < 4; ++rr){ \
        const h2 a2 = uph(a8[rr][kp]); \
        _Pragma("unroll") \
        for (int j = 0; j < 4; ++j){ \
          acc[rr][0][j] = FDOT2(a2, uph(q0_[j]), acc[rr][0][j]); \
          acc[rr][1][j] = FDOT2(a2, uph(q1_[j]), acc[rr][1][j]); \
          acc[rr][2][j] = FDOT2(a2, uph(q2_[j]), acc[rr][2][j]); } } }

    ui4 wA0,wA1,wA2,wA3,wA4,wA5, wB0,wB1,wB2,wB3,wB4,wB5;
    LDW1(wA0,wA1,wA2,wA3,wA4,wA5, 0);
    LDW1(wB0,wB1,wB2,wB3,wB4,wB5, 2);
    #pragma unroll 1
    for (int k0 = 0; k0 < 256; k0 += 8){
      const int nx = ((k0 + 8) & 255) >> 1;
      ui4 a8[4];
      #pragma unroll
      for (int rr = 0; rr < 4; ++rr)
        a8[rr] = *(const ui4*)&s_ctil[(4*rt+rr)*520 + 256 + k0];
      CMP1(0, wA0,wA1,wA2);
      CMP1(1, wA3,wA4,wA5);
      LDW1(wA0,wA1,wA2,wA3,wA4,wA5, nx);       // covered by kp 2,3
      CMP1(2, wB0,wB1,wB2);
      CMP1(3, wB3,wB4,wB5);
      LDW1(wB0,wB1,wB2,wB3,wB4,wB5, nx + 2);   // covered by next kp 0,1
    }
    #undef LDW1
    #undef CMP1
    #pragma unroll
    for (int rr = 0; rr < 4; ++rr){
      const int r = 4*rt + rr;
      ui2 v0 = {pk16(acc[rr][0][0], acc[rr][0][1]), pk16(acc[rr][0][2], acc[rr][0][3])};
      ui2 v1 = {pk16(acc[rr][1][0], acc[rr][1][1]), pk16(acc[rr][1][2], acc[rr][1][3])};
      *(ui2*)&s_ctil[r*520 + ct*4]       = v0;    // ctil cols ct*4..+3
      *(ui2*)&s_ctil[r*520 + 128 + ct*4] = v1;    // ctil cols 128+..
      *(f32x4*)&out[((long)(b0 + r) << 8) + ct*4] = acc[rr][2];
    }
  }

  // ---- Phase A pass 2: tiles {2,3} -> ctil cols 256..511 (post-loop write) ----
  {
    f32x4 acc[4][2];
    #pragma unroll
    for (int rr = 0; rr < 4; ++rr){ acc[rr][0] = (f32x4){0,0,0,0}; acc[rr][1] = (f32x4){0,0,0,0}; }

    #define LDW1B(p0_,p1_,p2_,p3_, kprow) { \
      const unsigned int* _w0 = W1P + (kprow)*640; \
      const unsigned int* _w1 = _w0 + 640; \
      p0_ = ((const ui4*)(_w0 + 256))[ct]; \
      p1_ = ((const ui4*)(_w0 + 384))[ct]; \
      p2_ = ((const ui4*)(_w1 + 256))[ct]; \
      p3_ = ((const ui4*)(_w1 + 384))[ct]; }
    #define CMP2(kp, q0_, q1_) { \
      _Pragma("unroll") \
      for (int rr = 0; rr < 4; ++rr){ \
        const h2 a2 = uph(a8[rr][kp]); \
        _Pragma("unroll") \
        for (int j = 0; j < 4; ++j){ \
          acc[rr][0][j] = FDOT2(a2, uph(q0_[j]), acc[rr][0][j]); \
          acc[rr][1][j] = FDOT2(a2, uph(q1_[j]), acc[rr][1][j]); } } }

    ui4 vA0,vA1,vA2,vA3, vB0,vB1,vB2,vB3;
    LDW1B(vA0,vA1,vA2,vA3, 0);
    LDW1B(vB0,vB1,vB2,vB3, 2);
    #pragma unroll 1
    for (int k0 = 0; k0 < 256; k0 += 8){
      const int nx = ((k0 + 8) & 255) >> 1;
      ui4 a8[4];
      #pragma unroll
      for (int rr = 0; rr < 4; ++rr)
        a8[rr] = *(const ui4*)&s_ctil[(4*rt+rr)*520 + 256 + k0];
      CMP2(0, vA0,vA1);
      CMP2(1, vA2,vA3);
      LDW1B(vA0,vA1,vA2,vA3, nx);
      CMP2(2, vB0,vB1);
      CMP2(3, vB2,vB3);
      LDW1B(vB0,vB1,vB2,vB3, nx + 2);
    }
    #undef LDW1B
    #undef CMP2
    // all center reads done; safe to overwrite cells 256..511 (same wave)
    #pragma unroll
    for (int rr = 0; rr < 4; ++rr){
      const int r = 4*rt + rr;
      ui2 v0 = {pk16(acc[rr][0][0], acc[rr][0][1]), pk16(acc[rr][0][2], acc[rr][0][3])};
      ui2 v1 = {pk16(acc[rr][1][0], acc[rr][1][1]), pk16(acc[rr][1][2], acc[rr][1][3])};
      *(ui2*)&s_ctil[r*520 + 256 + ct*4] = v0;    // ctil cols 256+..
      *(ui2*)&s_ctil[r*520 + 384 + ct*4] = v1;    // ctil cols 384+..
    }
  }
  // no barrier: ctil rows wave-local

  // ---- Phase B: attention, 8 rows/wave; reduce-scatter scores ----
  {
    const int myk = ((lane>>4)&1)*8 + ((lane>>3)&1)*4 + ((lane>>2)&1)*2 + ((lane>>1)&1);
    const int myh = lane >> 5;
    #pragma unroll 1
    for (int rr = 0; rr < 8; ++rr){
      const int r = wid*8 + rr;
      const long b = b0 + r;
      float4 c0, c1;
      {
        us4 h0 = *(const us4*)&s_ctil[r*520 + lane*4];
        us4 h1 = *(const us4*)&s_ctil[r*520 + 256 + lane*4];
        c0.x=h2f(h0[0]); c0.y=h2f(h0[1]); c0.z=h2f(h0[2]); c0.w=h2f(h0[3]);
        c1.x=h2f(h1[0]); c1.y=h2f(h1[1]); c1.z=h2f(h1[2]); c1.w=h2f(h1[3]);
      }
      float4 xv[16];
      const float* npt = nbr + ((b << 4) << 8) + lane*4;
      #pragma unroll
      for (int k = 0; k < 16; ++k) xv[k] = *(const float4*)(npt + (k << 8));
      float P0[16], P1[16];
      #pragma unroll
      for (int k = 0; k < 16; ++k){
        P0[k] = xv[k].x*c0.x + xv[k].y*c0.y + xv[k].z*c0.z + xv[k].w*c0.w;
        P1[k] = xv[k].x*c1.x + xv[k].y*c1.y + xv[k].z*c1.z + xv[k].w*c1.w;
      }
      // reduce-scatter: masks 32,16,8,4,2, then final 1
      const int b5 = lane & 32, b4 = lane & 16, b3 = lane & 8, b2 = lane & 4, b1 = lane & 2;
      float Q[16];
      #pragma unroll
      for (int j = 0; j < 16; ++j){
        const float give = b5 ? P0[j] : P1[j];
        const float keep = b5 ? P1[j] : P0[j];
        Q[j] = keep + __shfl_xor(give, 32, 64);
      }
      float R[8];
      #pragma unroll
      for (int j = 0; j < 8; ++j){
        const float give = b4 ? Q[j] : Q[8+j];
        const float keep = b4 ? Q[8+j] : Q[j];
        R[j] = keep + __shfl_xor(give, 16, 64);
      }
      float S[4];
      #pragma unroll
      for (int j = 0; j < 4; ++j){
        const float give = b3 ? R[j] : R[4+j];
        const float keep = b3 ? R[4+j] : R[j];
        S[j] = keep + __shfl_xor(give, 8, 64);
      }
      float T[2];
      #pragma unroll
      for (int j = 0; j < 2; ++j){
        const float give = b2 ? S[j] : S[2+j];
        const float keep = b2 ? S[2+j] : S[j];
        T[j] = keep + __shfl_xor(give, 4, 64);
      }
      float U;
      {
        const float give = b1 ? T[0] : T[1];
        const float keep = b1 ? T[1] : T[0];
        U = keep + __shfl_xor(give, 2, 64);
      }
      const float sfull = U + __shfl_xor(U, 1, 64);   // s[myh][myk]
      const float erk = ew[b*16 + myk];
      const float e = __expf(sfull*SCALE + erk);      // scores O(1): no max-sub
      float dn = e;
      dn += __shfl_xor(dn, 2, 64);
      dn += __shfl_xor(dn, 4, 64);
      dn += __shfl_xor(dn, 8, 64);
      dn += __shfl_xor(dn, 16, 64);
      const float w = e / dn;
      // broadcast via wave-local overlay of head1-ctil cells (c1 already read)
      float* wbuf = (float*)&s_ctil[r*520 + 256];
      wbuf[myh*16 + myk] = w;                         // 2 lanes same addr, same value
      f32x4 wv[8];
      #pragma unroll
      for (int t = 0; t < 8; ++t) wv[t] = ((const f32x4*)wbuf)[t];
      float4 agg0 = {0,0,0,0}, agg1 = {0,0,0,0};
      #pragma unroll
      for (int k = 0; k < 16; ++k){
        const float w0 = wv[k>>2][k&3];
        const float w1 = wv[4 + (k>>2)][k&3];
        agg0.x += w0*xv[k].x; agg0.y += w0*xv[k].y; agg0.z += w0*xv[k].z; agg0.w += w0*xv[k].w;
        agg1.x += w1*xv[k].x; agg1.y += w1*xv[k].y; agg1.z += w1*xv[k].z; agg1.w += w1*xv[k].w;
      }
      ui2 v0 = {pk16(agg0.x, agg0.y), pk16(agg0.z, agg0.w)};
      ui2 v1 = {pk16(agg1.x, agg1.y), pk16(agg1.z, agg1.w)};
      *(ui2*)&s_ctil[r*520 + lane*4]       = v0;   // agg0 (WAR on own cells)
      *(ui2*)&s_ctil[r*520 + 256 + lane*4] = v1;   // agg1 (overwrites wbuf after read)
    }
  }
  // no barrier: agg rows wave-local

  // ---- Phase C (+fused LayerNorm): ctx in registers -> ctx_n packed f16 ----
  {
    f32x4 cacc[4][2];
    #pragma unroll
    for (int rr = 0; rr < 4; ++rr){ cacc[rr][0] = (f32x4){0,0,0,0}; cacc[rr][1] = (f32x4){0,0,0,0}; }

    #define LDW2(p0_,p1_,p2_,p3_, kprow) { \
      const unsigned int* _w0 = W2P + (kprow)*256; \
      const unsigned int* _w1 = _w0 + 256; \
      p0_ = ((const ui4*)(_w0      ))[ct]; \
      p1_ = ((const ui4*)(_w0 + 128))[ct]; \
      p2_ = ((const ui4*)(_w1      ))[ct]; \
      p3_ = ((const ui4*)(_w1 + 128))[ct]; }
    #define CMPC(kp, q0_, q1_) { \
      _Pragma("unroll") \
      for (int rr = 0; rr < 4; ++rr){ \
        const h2 x0 = uph(a0[rr][kp]); \
        const h2 x1 = uph(a1[rr][kp]); \
        _Pragma("unroll") \
        for (int j = 0; j < 4; ++j){ \
          cacc[rr][0][j] = FDOT2(x0, uph(q0_[j]), cacc[rr][0][j]); \
          cacc[rr][1][j] = FDOT2(x1, uph(q1_[j]), cacc[rr][1][j]); } } }

    ui4 cA0,cA1,cA2,cA3, cB0,cB1,cB2,cB3;
    LDW2(cA0,cA1,cA2,cA3, 0);
    LDW2(cB0,cB1,cB2,cB3, 2);
    #pragma unroll 1
    for (int k0 = 0; k0 < 256; k0 += 8){
      const int nx = ((k0 + 8) & 255) >> 1;
      ui4 a0[4], a1[4];
      #pragma unroll
      for (int rr = 0; rr < 4; ++rr){
        a0[rr] = *(const ui4*)&s_ctil[(4*rt+rr)*520 + k0];
        a1[rr] = *(const ui4*)&s_ctil[(4*rt+rr)*520 + 256 + k0];
      }
      CMPC(0, cA0,cA1);
      CMPC(1, cA2,cA3);
      LDW2(cA0,cA1,cA2,cA3, nx);
      CMPC(2, cB0,cB1);
      CMPC(3, cB2,cB3);
      LDW2(cB0,cB1,cB2,cB3, nx + 2);
    }
    #undef LDW2
    #undef CMPC
    // fused LayerNorm across the 32 ct-lanes of each rt group
    const f32x4 gv0 = ((const f32x4*)gamma)[ct], gv1 = ((const f32x4*)gamma)[32 + ct];
    const f32x4 bv0 = ((const f32x4*)beta )[ct], bv1 = ((const f32x4*)beta )[32 + ct];
    #pragma unroll
    for (int rr = 0; rr < 4; ++rr){
      float s = 0.f, q = 0.f;
      #pragma unroll
      for (int t = 0; t < 2; ++t)
        #pragma unroll
        for (int j = 0; j < 4; ++j){
          const float x = cacc[rr][t][j];
          s += x; q += x*x;
        }
      #pragma unroll
      for (int m = 16; m >= 1; m >>= 1){
        s += __shfl_xor(s, m, 64);
        q += __shfl_xor(q, m, 64);
      }
      const float mu  = s * (1.f/256.f);
      const float var = q * (1.f/256.f) - mu*mu;
      const float rs  = rsqrtf(var + 1e-5f);
      const int r = 4*rt + rr;
      float y0[4], y1[4];
      #pragma unroll
      for (int j = 0; j < 4; ++j){
        y0[j] = (cacc[rr][0][j] - mu)*rs*gv0[j] + bv0[j];
        y1[j] = (cacc[rr][1][j] - mu)*rs*gv1[j] + bv1[j];
      }
      ui2 v0 = {pk16(y0[0], y0[1]), pk16(y0[2], y0[3])};
      ui2 v1 = {pk16(y1[0], y1[1]), pk16(y1[2], y1[3])};
      *(ui2*)&s_ctil[r*520 + ct*4]       = v0;   // ctx_n cols ct*4..+3
      *(ui2*)&s_ctil[r*520 + 128 + ct*4] = v1;   // ctx_n cols 128+..
    }
  }
  // no barrier: ctx_n rows wave-local

  // ---- Phase E: out-right = ctx_n @ Wx^T ----
  {
    f32x4 eacc[4];
    #pragma unroll
    for (int rr = 0; rr < 4; ++rr) eacc[rr] = (f32x4){0,0,0,0};

    #define LDW3(p0_,p1_, kprow) { \
      const unsigned int* _w0 = W3P + (kprow)*128; \
      p0_ = ((const ui4*)(_w0      ))[ct]; \
      p1_ = ((const ui4*)(_w0 + 128))[ct]; }
    #define CMPE(kp, q_) { \
      _Pragma("unroll") \
      for (int rr = 0; rr < 4; ++rr){ \
        const h2 x = uph(a8[rr][kp]); \
        _Pragma("unroll") \
        for (int j = 0; j < 4; ++j) \
          eacc[rr][j] = FDOT2(x, uph(q_[j]), eacc[rr][j]); } }

    ui4 eA0,eA1, eB0,eB1;
    LDW3(eA0,eA1, 0);
    LDW3(eB0,eB1, 2);
    #pragma unroll 1
    for (int k0 = 0; k0 < 256; k0 += 8){
      const int nx = ((k0 + 8) & 255) >> 1;
      ui4 a8[4];
      #pragma unroll
      for (int rr = 0; rr < 4; ++rr)
        a8[rr] = *(const ui4*)&s_ctil[(4*rt+rr)*520 + k0];
      CMPE(0, eA0);
      CMPE(1, eA1);
      LDW3(eA0,eA1, nx);
      CMPE(2, eB0);
      CMPE(3, eB1);
      LDW3(eB0,eB1, nx + 2);
    }
    #undef LDW3
    #undef CMPE
    #pragma unroll
    for (int rr = 0; rr < 4; ++rr)
      *(f32x4*)&out[((long)(b0 + 4*rt + rr) << 8) + 128 + ct*4] = eacc[rr];
  }
}

extern "C" void kernel_launch(void* const* d_in, const int* in_sizes, int n_in,
                              void* d_out, int out_size, void* d_ws, size_t ws_size,
                              hipStream_t stream){
  const float* center = (const float*)d_in[0];
  const float* nbr    = (const float*)d_in[1];
  const float* ew     = (const float*)d_in[2];
  const float* Wq     = (const float*)d_in[3];
  const float* Wk     = (const float*)d_in[4];
  const float* Wv     = (const float*)d_in[5];
  const float* Wc     = (const float*)d_in[6];
  const float* Wx     = (const float*)d_in[7];
  const float* gamma  = (const float*)d_in[8];
  const float* beta   = (const float*)d_in[9];
  (void)in_sizes; (void)n_in; (void)out_size;

  unsigned int* W = (unsigned int*)d_ws;   // 512 KiB of workspace
  (void)ws_size;

  prep_kernel<<<1024, 256, 0, stream>>>(Wq, Wk, Wv, Wc, Wx, W);
  fused_kernel<<<Bsz/BR, 256, 0, stream>>>(center, nbr, ew, gamma, beta, W, (float*)d_out);
}